// Round 1
// baseline (49.087 us; speedup 1.0000x reference)
//
#include <hip/hip_runtime.h>
#include <hip/hip_bf16.h>

typedef __attribute__((ext_vector_type(8))) short short8;
typedef __attribute__((ext_vector_type(4))) float f32x4;

#define N_ENS 16
#define D_IN 784
#define D_HID 128
#define D_OUT 10
#define KPAD 800
#define NKT 25            // K tiles of 32 (784 padded to 800)
#define BM 64
#define TILE_B_BYTES 8192 // 128 cols x 32 k x 2B (bf16), swizzled image
#define WS_B1 204800      // NKT*8192
#define WS_W2 205312      // + 128*4
#define WS_B2 210432      // + 1280*4

// RNE float->bf16, version-proof (inputs are finite)
__device__ __forceinline__ unsigned short f2bf(float f) {
  unsigned int u = __float_as_uint(f);
  return (unsigned short)((u + 0x7FFFu + ((u >> 16) & 1u)) >> 16);
}

__device__ __forceinline__ void gload_lds16(const void* g, void* l) {
  __builtin_amdgcn_global_load_lds((const __attribute__((address_space(1))) void*)g,
                                   (__attribute__((address_space(3))) void*)l, 16, 0, 0);
}

// XOR swizzle: byte offset within a [rows][32 bf16] tile (64B rows), 16B granules
__device__ __forceinline__ int swz(int row, int byte_in_row) {
  return ((row << 6) | byte_in_row) ^ ((row & 7) << 4);
}

// ---------------- prep: combine ensemble -> ws ----------------
__global__ void prep_kernel(const float* __restrict__ fc_w, const float* __restrict__ fc_b,
                            const float* __restrict__ cls_w, const float* __restrict__ cls_b,
                            const float* __restrict__ factor, char* __restrict__ ws) {
  int tid = blockIdx.x * 256 + threadIdx.x;
  float f[N_ENS];
#pragma unroll
  for (int e = 0; e < N_ENS; ++e) f[e] = factor[e];

  if (tid < D_HID * KPAD) {                       // 102400: w1 bf16, swizzled tiles
    int col = tid / KPAD;
    int k   = tid - col * KPAD;
    float v = 0.f;
    if (k < D_IN) {
#pragma unroll
      for (int e = 0; e < N_ENS; ++e) v += f[e] * fc_w[(size_t)(e * D_HID + col) * D_IN + k];
    }
    int kt = k >> 5, kk = k & 31;
    *(unsigned short*)(ws + kt * TILE_B_BYTES + swz(col, kk * 2)) = f2bf(v);
  } else if (tid < D_HID * KPAD + D_HID) {        // b1
    int col = tid - D_HID * KPAD;
    float v = 0.f;
#pragma unroll
    for (int e = 0; e < N_ENS; ++e) v += f[e] * fc_b[e * D_HID + col];
    *(float*)(ws + WS_B1 + col * 4) = v;
  } else if (tid < D_HID * KPAD + D_HID + D_HID * D_OUT) {  // w2t[n][o]
    int i = tid - (D_HID * KPAD + D_HID);
    int n = i / D_OUT, o = i - n * D_OUT;
    float v = 0.f;
#pragma unroll
    for (int e = 0; e < N_ENS; ++e) v += f[e] * cls_w[(e * D_OUT + o) * D_HID + n];
    *(float*)(ws + WS_W2 + i * 4) = v;
  } else if (tid < D_HID * KPAD + D_HID + D_HID * D_OUT + D_OUT) {  // b2
    int o = tid - (D_HID * KPAD + D_HID + D_HID * D_OUT);
    float v = 0.f;
#pragma unroll
    for (int e = 0; e < N_ENS; ++e) v += f[e] * cls_b[e * D_OUT + o];
    *(float*)(ws + WS_B2 + o * 4) = v;
  }
}

// ---------------- main: fused GEMM1(relu) + GEMM2 ----------------
// block: 256 thr (4 waves, 2x2 wave grid), tile 64(M) x 128(N), BK=32
__global__ __launch_bounds__(256, 4) void mnist_fused(const float* __restrict__ x,
                                                      const char* __restrict__ ws,
                                                      float* __restrict__ out) {
  // LDS: staging A0@0(4K) A1@4K B0@8K B1@16K (24K total)
  // epilogue (after final barrier, reuses region): h[64][129] f32 @0 (33024B), red @33024 (2560B)
  __shared__ char smem[35584];
  const int tid = threadIdx.x;
  const int lane = tid & 63;
  const int w  = tid >> 6;
  const int wr = w >> 1, wc = w & 1;
  const int kg = lane >> 4, l15 = lane & 15;
  const int m0 = blockIdx.x * BM;

  // A staging mapping: thread -> (row, 16B k-granule)
  const int arow = tid >> 2, aq = tid & 3;
  const float* xrow = x + (size_t)(m0 + arow) * D_IN;
  const int awbyte = swz(arow, aq << 4);

  f32x4 acc[2][4];
#pragma unroll
  for (int mi = 0; mi < 2; ++mi)
#pragma unroll
    for (int ni = 0; ni < 4; ++ni) acc[mi][ni] = f32x4{0.f, 0.f, 0.f, 0.f};

  float xv[8];

  // ---- prologue: stage kt=0 into buffer 0
  {
    const float4 v0 = *(const float4*)(xrow + aq * 8);
    const float4 v1 = *(const float4*)(xrow + aq * 8 + 4);
    xv[0]=v0.x; xv[1]=v0.y; xv[2]=v0.z; xv[3]=v0.w;
    xv[4]=v1.x; xv[5]=v1.y; xv[6]=v1.z; xv[7]=v1.w;
  }
#pragma unroll
  for (int i = 0; i < 2; ++i)
    gload_lds16(ws + w * 2048 + i * 1024 + lane * 16, smem + 8192 + w * 2048 + i * 1024);
  {
    union { unsigned short u[8]; short8 s; } pk;
#pragma unroll
    for (int j = 0; j < 8; ++j) pk.u[j] = f2bf(xv[j]);
    *(short8*)(smem + awbyte) = pk.s;
  }
  __syncthreads();

  for (int kt = 0; kt < NKT; ++kt) {
    const int cur = kt & 1, nb = cur ^ 1;
    const bool more = (kt + 1) < NKT;
    if (more) {
      const int ktn = kt + 1;
#pragma unroll
      for (int i = 0; i < 2; ++i)
        gload_lds16(ws + ktn * TILE_B_BYTES + w * 2048 + i * 1024 + lane * 16,
                    smem + 8192 + nb * 8192 + w * 2048 + i * 1024);
      const int k0 = ktn * 32 + aq * 8;
      if (k0 < D_IN) {
        const float4 v0 = *(const float4*)(xrow + k0);
        const float4 v1 = *(const float4*)(xrow + k0 + 4);
        xv[0]=v0.x; xv[1]=v0.y; xv[2]=v0.z; xv[3]=v0.w;
        xv[4]=v1.x; xv[5]=v1.y; xv[6]=v1.z; xv[7]=v1.w;
      } else {
#pragma unroll
        for (int j = 0; j < 8; ++j) xv[j] = 0.f;
      }
    }
    // compute on cur
    {
      const char* Ab = smem + cur * 4096;
      const char* Bb = smem + 8192 + cur * 8192;
      short8 a[2], b[4];
#pragma unroll
      for (int mi = 0; mi < 2; ++mi) {
        const int r = wr * 32 + mi * 16 + l15;
        a[mi] = *(const short8*)(Ab + swz(r, kg << 4));
      }
#pragma unroll
      for (int ni = 0; ni < 4; ++ni) {
        const int c = wc * 64 + ni * 16 + l15;
        b[ni] = *(const short8*)(Bb + swz(c, kg << 4));
      }
#pragma unroll
      for (int mi = 0; mi < 2; ++mi)
#pragma unroll
        for (int ni = 0; ni < 4; ++ni)
          acc[mi][ni] = __builtin_amdgcn_mfma_f32_16x16x32_bf16(a[mi], b[ni], acc[mi][ni], 0, 0, 0);
    }
    if (more) {
      union { unsigned short u[8]; short8 s; } pk;
#pragma unroll
      for (int j = 0; j < 8; ++j) pk.u[j] = f2bf(xv[j]);
      *(short8*)(smem + nb * 4096 + awbyte) = pk.s;
    }
    __syncthreads();
  }

  // ---- epilogue 1: h = relu(acc + b1) -> LDS [64][129]
  const float* b1 = (const float*)(ws + WS_B1);
  float* h = (float*)smem;
#pragma unroll
  for (int ni = 0; ni < 4; ++ni) {
    const int n = wc * 64 + ni * 16 + l15;
    const float bv = b1[n];
#pragma unroll
    for (int mi = 0; mi < 2; ++mi) {
      const int rb = wr * 32 + mi * 16 + kg * 4;
#pragma unroll
      for (int j = 0; j < 4; ++j) {
        float v = acc[mi][ni][j] + bv;
        h[(rb + j) * 129 + n] = v > 0.f ? v : 0.f;
      }
    }
  }
  __syncthreads();

  // ---- epilogue 2: out = h @ w2t + b2 (w2t reads are wave-uniform -> scalarized)
  const float* w2t = (const float*)(ws + WS_W2);
  const float* b2  = (const float*)(ws + WS_B2);
  float po[10];
#pragma unroll
  for (int o = 0; o < 10; ++o) po[o] = 0.f;
  const int m = tid & 63;
  const int half = (tid >> 6) & 1;
  if (tid < 128) {
    const float* hr  = h + m * 129 + half * 64;
    const float* wr2 = w2t + half * 64 * D_OUT;
    for (int n = 0; n < 64; ++n) {
      const float hv = hr[n];
#pragma unroll
      for (int o = 0; o < 10; ++o) po[o] += hv * wr2[n * 10 + o];
    }
  }
  float* red = (float*)(smem + 33024);
  if (tid >= 64 && tid < 128) {
#pragma unroll
    for (int o = 0; o < 10; ++o) red[m * 10 + o] = po[o];
  }
  __syncthreads();
  if (tid < 64) {
    float* op = out + (size_t)(m0 + m) * 10;
#pragma unroll
    for (int o = 0; o < 10; o += 2) {
      float2 v;
      v.x = po[o]     + red[m * 10 + o]     + b2[o];
      v.y = po[o + 1] + red[m * 10 + o + 1] + b2[o + 1];
      *(float2*)(op + o) = v;
    }
  }
}

extern "C" void kernel_launch(void* const* d_in, const int* in_sizes, int n_in,
                              void* d_out, int out_size, void* d_ws, size_t ws_size,
                              hipStream_t stream) {
  const float* x      = (const float*)d_in[0];
  const float* fc_w   = (const float*)d_in[1];
  const float* fc_b   = (const float*)d_in[2];
  const float* cls_w  = (const float*)d_in[3];
  const float* cls_b  = (const float*)d_in[4];
  const float* factor = (const float*)d_in[5];
  char* ws = (char*)d_ws;
  float* outp = (float*)d_out;

  // 102400 + 128 + 1280 + 10 = 103818 work items
  prep_kernel<<<406, 256, 0, stream>>>(fc_w, fc_b, cls_w, cls_b, factor, ws);
  mnist_fused<<<1024, 256, 0, stream>>>(x, ws, outp);
}